// Round 7
// baseline (278.612 us; speedup 1.0000x reference)
//
#include <hip/hip_runtime.h>
#include <hip/hip_bf16.h>
#include <cstdint>
#include <cstddef>

#define NB 64      // batch
#define DD 256     // model dim
#define NN 625     // tokens = 25*25
#define NP 640     // padded token rows
#define NH 8       // heads
#define DH 32      // head dim
#define N3 768     // 3*DD
#define BSTR 640   // padded bias stride
#define LDK 72     // GEMM LDS row pad (elements)

typedef __attribute__((ext_vector_type(8))) short bf16x8;
typedef __attribute__((ext_vector_type(4))) float f32x4;
typedef unsigned int u32;

__device__ __forceinline__ unsigned short f2bf(float f) {
    u32 x = __builtin_bit_cast(u32, f);
    return (unsigned short)((x + 0x7fffu + ((x >> 16) & 1u)) >> 16);   // RNE
}
__device__ __forceinline__ u32 cvt_pk_bf16(float a, float b) {
    u32 r;
    asm("v_cvt_pk_bf16_f32 %0, %1, %2" : "=v"(r) : "v"(a), "v"(b));
    return r;
}

// ---------------------------------------------------------------------------
// x (b, 256, 625) fp32  ->  XT (b, 640, 256) bf16  (transpose + cast; pad = 0)
// ---------------------------------------------------------------------------
__global__ __launch_bounds__(256)
void xT_kernel(const float* __restrict__ x, unsigned short* __restrict__ XT)
{
    __shared__ float T[64][65];
    const int b = blockIdx.z, n0 = blockIdx.x * 64, d0 = blockIdx.y * 64;
    const int tid = threadIdx.x;
    const float* xb = x + (size_t)b * DD * NN;
    #pragma unroll
    for (int r = 0; r < 16; ++r) {
        const int flat = r * 256 + tid;
        const int dd = flat >> 6, ii = flat & 63;      // ii fast: coalesced read
        const int n = n0 + ii;
        T[dd][ii] = (n < NN) ? xb[(size_t)(d0 + dd) * NN + n] : 0.f;
    }
    __syncthreads();
    #pragma unroll
    for (int r = 0; r < 16; ++r) {
        const int flat = r * 256 + tid;
        const int ii = flat >> 6, dd = flat & 63;      // dd fast: coalesced write
        XT[((size_t)b * NP + n0 + ii) * DD + d0 + dd] = f2bf(T[dd][ii]);
    }
}

// ---------------------------------------------------------------------------
// Generic transpose-cast: src (R x C) fp32 -> dst (C x R) bf16.  R,C % 64 == 0.
// ---------------------------------------------------------------------------
__global__ __launch_bounds__(256)
void transpose_cast(const float* __restrict__ src, unsigned short* __restrict__ dst,
                    int R, int C)
{
    __shared__ float T[64][65];
    const int c0 = blockIdx.x * 64, r0 = blockIdx.y * 64;
    const int tid = threadIdx.x;
    #pragma unroll
    for (int r = 0; r < 16; ++r) {
        const int flat = r * 256 + tid;
        const int rr = flat >> 6, cc = flat & 63;
        T[rr][cc] = src[(size_t)(r0 + rr) * C + c0 + cc];
    }
    __syncthreads();
    #pragma unroll
    for (int r = 0; r < 16; ++r) {
        const int flat = r * 256 + tid;
        const int cc = flat >> 6, rr = flat & 63;
        dst[(size_t)(c0 + cc) * R + r0 + rr] = f2bf(T[rr][cc]);
    }
}

// ---------------------------------------------------------------------------
// Bias gather into NATURAL (h, i, j) layout, 640x640 padded, pad = 0.
// No transpose needed -> no LDS; rel read and bias writes both j-coalesced.
// ---------------------------------------------------------------------------
__global__ __launch_bounds__(256)
void bias2_kernel(const int* __restrict__ rel, const float* __restrict__ table,
                  float* __restrict__ bias2)
{
    const int i0 = blockIdx.x * 64, j0 = blockIdx.y * 64;
    const int tid = threadIdx.x;
    #pragma unroll
    for (int r = 0; r < 16; ++r) {
        const int flat = r * 256 + tid;
        const int ii = flat >> 6, jj = flat & 63;
        const int iG = i0 + ii, jG = j0 + jj;
        const int idx = (iG < NN && jG < NN) ? rel[(size_t)iG * NN + jG] : -1;
        #pragma unroll
        for (int h = 0; h < NH; ++h)
            bias2[((size_t)h * BSTR + iG) * BSTR + jG] = (idx >= 0) ? table[idx * NH + h] : 0.f;
    }
}

// ---------------------------------------------------------------------------
// QKV GEMM, m93-style (unchanged from R5).
// ---------------------------------------------------------------------------
__global__ __launch_bounds__(256)
void qkv_mfma(const unsigned short* __restrict__ XT, const unsigned short* __restrict__ WT,
              unsigned short* __restrict__ Q, unsigned short* __restrict__ K,
              unsigned short* __restrict__ V)
{
    __shared__ unsigned short As[128][LDK];
    __shared__ unsigned short Bs[128][LDK];

    const int b = blockIdx.z, i0 = blockIdx.x * 128, j0 = blockIdx.y * 128;
    const int tid = threadIdx.x, lane = tid & 63, w = tid >> 6;
    const int lo = lane & 15, hi = lane >> 4;
    const int wr = w >> 1, wc = w & 1;

    const unsigned short* Abase = XT + (size_t)b * NP * DD;
    const unsigned short* Bbase = WT;

    const int srow = tid >> 3;
    const int sc   = (tid & 7) * 8;

    f32x4 acc[4][4];
    #pragma unroll
    for (int a = 0; a < 4; ++a)
        #pragma unroll
        for (int t = 0; t < 4; ++t) acc[a][t] = (f32x4){0.f, 0.f, 0.f, 0.f};

    for (int k0 = 0; k0 < DD; k0 += 64) {
        #pragma unroll
        for (int p = 0; p < 4; ++p) {
            const int row = p * 32 + srow;
            *(bf16x8*)&As[row][sc] = *(const bf16x8*)&Abase[(size_t)(i0 + row) * DD + k0 + sc];
            *(bf16x8*)&Bs[row][sc] = *(const bf16x8*)&Bbase[(size_t)(j0 + row) * DD + k0 + sc];
        }
        __syncthreads();
        #pragma unroll
        for (int kk = 0; kk < 64; kk += 32) {
            bf16x8 af[4], bfr[4];
            #pragma unroll
            for (int a = 0; a < 4; ++a)
                af[a] = *(const bf16x8*)&As[wr * 64 + a * 16 + lo][kk + 8 * hi];
            #pragma unroll
            for (int t = 0; t < 4; ++t)
                bfr[t] = *(const bf16x8*)&Bs[wc * 64 + t * 16 + lo][kk + 8 * hi];
            #pragma unroll
            for (int a = 0; a < 4; ++a)
                #pragma unroll
                for (int t = 0; t < 4; ++t)
                    acc[a][t] = __builtin_amdgcn_mfma_f32_16x16x32_bf16(af[a], bfr[t], acc[a][t], 0, 0, 0);
        }
        __syncthreads();
    }

    #pragma unroll
    for (int t = 0; t < 4; ++t) {
        const int j  = j0 + wc * 64 + t * 16 + lo;
        const int tt = j >> 8;
        const int h  = (j & 255) >> 5;
        const int cb = j & 31;
        unsigned short* dst = (tt == 0) ? Q : (tt == 1) ? K : V;
        const float mul = (tt == 0) ? 0.17677669529663687f : 1.f;
        #pragma unroll
        for (int a = 0; a < 4; ++a) {
            #pragma unroll
            for (int r = 0; r < 4; ++r) {
                const int i = i0 + wr * 64 + a * 16 + 4 * hi + r;
                if (i < NN)
                    dst[(((size_t)b * NH + h) * NN + i) * DH + cb] = f2bf(acc[a][t][r] * mul);
            }
        }
    }
}

// ---------------------------------------------------------------------------
// MFMA flash attention, R7: swapped QK^T (S^T = K.Q^T, lane-local P rows),
// in-register P redistribution (cvt_pk + 8 shfl), K/bias direct from global,
// full V-transposed staged ONCE in swizzled LDS -> ZERO main-loop barriers.
// ---------------------------------------------------------------------------
__global__ __launch_bounds__(256, 4)
void attn_kernel(const unsigned short* __restrict__ Q,
                 const unsigned short* __restrict__ K,
                 const unsigned short* __restrict__ V,
                 const float* __restrict__ bias2, unsigned short* __restrict__ AO)
{
    __shared__ unsigned short Vt[DH][640];   // [d][j], col stored at j ^ ((d&7)<<3)

    const int b  = blockIdx.z;
    const int h  = blockIdx.y;
    const int i0 = blockIdx.x * 64;
    const int tid  = threadIdx.x;
    const int lane = tid & 63;
    const int w    = tid >> 6;
    const int lo   = lane & 15;
    const int hi   = lane >> 4;

    const size_t hoff = ((size_t)b * NH + h) * (size_t)NN * DH;

    // ---- stage ALL of V transposed + swizzled; the only barrier follows ----
    {
        const int jr = tid & 63;
        const int sc = (tid >> 6) * 8;
        for (int it = 0; it < 10; ++it) {
            const int j = it * 64 + jr;
            bf16x8 vv = {0, 0, 0, 0, 0, 0, 0, 0};
            if (j < NN) vv = *(const bf16x8*)&V[hoff + (size_t)j * DH + sc];
            #pragma unroll
            for (int e = 0; e < 8; ++e)
                Vt[sc + e][j ^ (((sc + e) & 7) << 3)] = (unsigned short)vv[e];
        }
    }

    // Q B-fragment: col q = i0+16w+lo, k = 8hi..8hi+7 (clamped row)
    const int iq  = i0 + w * 16 + lo;
    const int iqc = (iq < NN) ? iq : (NN - 1);
    const bf16x8 qf = *(const bf16x8*)&Q[hoff + (size_t)iqc * DH + 8 * hi];

    // bias row for this lane's q (pad rows are allocated & zero)
    const float* bb = bias2 + ((size_t)h * BSTR + iq) * BSTR;

    __syncthreads();

    f32x4 acc0 = {0.f, 0.f, 0.f, 0.f};
    f32x4 acc1 = {0.f, 0.f, 0.f, 0.f};
    float lsum = 0.f;

    const int src0 = lo + ((hi & 1) << 5);   // lane (lo, hi'=2*(hi&1))
    const int src1 = src0 + 16;
    const bool selA = (hi < 2);
    const int swz = (lo & 7) << 3;

    #pragma unroll 2
    for (int ss = 0; ss < 20; ++ss) {
        const int jb = ss * 32;
        // K A-fragments direct from global (rows clamped to valid data)
        const int kr0 = jb + lo, kr1 = jb + 16 + lo;
        const bf16x8 kf0 = *(const bf16x8*)&K[hoff + (size_t)(kr0 < NN ? kr0 : NN - 1) * DH + 8 * hi];
        const bf16x8 kf1 = *(const bf16x8*)&K[hoff + (size_t)(kr1 < NN ? kr1 : NN - 1) * DH + 8 * hi];
        // bias C operands: contiguous over j
        const f32x4 b0 = *(const f32x4*)&bb[jb + 4 * hi];
        const f32x4 b1 = *(const f32x4*)&bb[jb + 16 + 4 * hi];
        // S^T: lane(lo,hi) reg r = S[q=lo][j=jb(+16)+4hi+r] + bias
        const f32x4 s0 = __builtin_amdgcn_mfma_f32_16x16x32_bf16(kf0, qf, b0, 0, 0, 0);
        const f32x4 s1 = __builtin_amdgcn_mfma_f32_16x16x32_bf16(kf1, qf, b1, 0, 0, 0);

        float p0[4], p1[4];
        #pragma unroll
        for (int r = 0; r < 4; ++r) {
            const bool m0 = (jb + 4 * hi + r) < NN;
            const bool m1 = (jb + 16 + 4 * hi + r) < NN;
            p0[r] = m0 ? __expf(s0[r]) : 0.f;
            p1[r] = m1 ? __expf(s1[r]) : 0.f;
            lsum += p0[r] + p1[r];
        }
        // pack P to bf16 words: A0=(j+4hi'+0,1) A1=(+2,3) of s0; B0/B1 of s1
        const u32 A0 = cvt_pk_bf16(p0[0], p0[1]);
        const u32 A1 = cvt_pk_bf16(p0[2], p0[3]);
        const u32 B0 = cvt_pk_bf16(p1[0], p1[1]);
        const u32 B1 = cvt_pk_bf16(p1[2], p1[3]);
        // redistribute: lane(lo,hi) A-frag needs P[q=lo][j=jb+8hi+e]
        const u32 a0 = __shfl(A0, src0, 64), c0 = __shfl(B0, src0, 64);
        const u32 a1 = __shfl(A1, src0, 64), c1 = __shfl(B1, src0, 64);
        const u32 a2 = __shfl(A0, src1, 64), c2 = __shfl(B0, src1, 64);
        const u32 a3 = __shfl(A1, src1, 64), c3 = __shfl(B1, src1, 64);
        union { u32 u[4]; bf16x8 v; } P;
        P.u[0] = selA ? a0 : c0;
        P.u[1] = selA ? a1 : c1;
        P.u[2] = selA ? a2 : c2;
        P.u[3] = selA ? a3 : c3;
        // V B-fragments from swizzled LDS
        const bf16x8 vf0 = *(const bf16x8*)&Vt[lo][(jb + 8 * hi) ^ swz];
        const bf16x8 vf1 = *(const bf16x8*)&Vt[16 + lo][(jb + 8 * hi) ^ swz];
        acc0 = __builtin_amdgcn_mfma_f32_16x16x32_bf16(P.v, vf0, acc0, 0, 0, 0);
        acc1 = __builtin_amdgcn_mfma_f32_16x16x32_bf16(P.v, vf1, acc1, 0, 0, 0);
    }

    // row sums: lane holds partial for q=lo; sum across the 4 hi-groups
    lsum += __shfl_xor(lsum, 16, 64);
    lsum += __shfl_xor(lsum, 32, 64);
    const float inv = 1.f / lsum;

    // epilogue: acc0[r] = O[q=4hi+r][d=lo]; fetch inv for q=4hi+r via shfl
    #pragma unroll
    for (int r = 0; r < 4; ++r) {
        const int i = i0 + w * 16 + 4 * hi + r;
        const float invr = __shfl(inv, 4 * hi + r, 64);
        if (i < NN) {
            unsigned short* dst = AO + ((size_t)b * NP + i) * DD + h * DH;
            dst[lo]      = f2bf(acc0[r] * invr);
            dst[16 + lo] = f2bf(acc1[r] * invr);
        }
    }
}

// ---------------------------------------------------------------------------
// Output projection, m93-style (unchanged from R5).
// ---------------------------------------------------------------------------
__global__ __launch_bounds__(256)
void outproj_mfma(const unsigned short* __restrict__ AO, const unsigned short* __restrict__ WoT,
                  float* __restrict__ out)
{
    __shared__ unsigned short As[128][LDK];
    __shared__ unsigned short Bs[128][LDK];

    const int b = blockIdx.z, i0 = blockIdx.x * 128, j0 = blockIdx.y * 128;
    const int tid = threadIdx.x, lane = tid & 63, w = tid >> 6;
    const int lo = lane & 15, hi = lane >> 4;
    const int wr = w >> 1, wc = w & 1;

    const unsigned short* Abase = AO + (size_t)b * NP * DD;

    const int srow = tid >> 3;
    const int sc   = (tid & 7) * 8;

    f32x4 acc[4][4];
    #pragma unroll
    for (int a = 0; a < 4; ++a)
        #pragma unroll
        for (int t = 0; t < 4; ++t) acc[a][t] = (f32x4){0.f, 0.f, 0.f, 0.f};

    for (int k0 = 0; k0 < DD; k0 += 64) {
        #pragma unroll
        for (int p = 0; p < 4; ++p) {
            const int row = p * 32 + srow;
            *(bf16x8*)&As[row][sc] = *(const bf16x8*)&Abase[(size_t)(i0 + row) * DD + k0 + sc];
            *(bf16x8*)&Bs[row][sc] = *(const bf16x8*)&WoT[(size_t)(j0 + row) * DD + k0 + sc];
        }
        __syncthreads();
        #pragma unroll
        for (int kk = 0; kk < 64; kk += 32) {
            bf16x8 af[4], bfr[4];
            #pragma unroll
            for (int a = 0; a < 4; ++a)
                af[a] = *(const bf16x8*)&As[wr * 64 + a * 16 + lo][kk + 8 * hi];
            #pragma unroll
            for (int t = 0; t < 4; ++t)
                bfr[t] = *(const bf16x8*)&Bs[wc * 64 + t * 16 + lo][kk + 8 * hi];
            #pragma unroll
            for (int a = 0; a < 4; ++a)
                #pragma unroll
                for (int t = 0; t < 4; ++t)
                    acc[a][t] = __builtin_amdgcn_mfma_f32_16x16x32_bf16(af[a], bfr[t], acc[a][t], 0, 0, 0);
        }
        __syncthreads();
    }

    #pragma unroll
    for (int t = 0; t < 4; ++t) {
        const int j = j0 + wc * 64 + t * 16 + lo;
        float* dst = out + ((size_t)b * DD + j) * NN;
        #pragma unroll
        for (int a = 0; a < 4; ++a) {
            #pragma unroll
            for (int r = 0; r < 4; ++r) {
                const int i = i0 + wr * 64 + a * 16 + 4 * hi + r;
                if (i < NN) dst[i] = acc[a][t][r];
            }
        }
    }
}

// ---------------------------------------------------------------------------
extern "C" void kernel_launch(void* const* d_in, const int* in_sizes, int n_in,
                              void* d_out, int out_size, void* d_ws, size_t ws_size,
                              hipStream_t stream)
{
    (void)in_sizes; (void)n_in; (void)out_size; (void)ws_size;
    const float* x     = (const float*)d_in[0];
    const float* w_qkv = (const float*)d_in[1];
    const float* w_out = (const float*)d_in[2];
    const float* table = (const float*)d_in[3];
    const int*   rel   = (const int*)d_in[4];
    float* out = (float*)d_out;

    unsigned short* ws16 = (unsigned short*)d_ws;
    const size_t szQ  = (size_t)NB * NH * NN * DH;   // 10,240,000
    const size_t szXT = (size_t)NB * NP * DD;        // 10,485,760
    unsigned short* Q   = ws16;
    unsigned short* K   = Q + szQ;
    unsigned short* V   = K + szQ;
    unsigned short* XT  = V + szQ;
    unsigned short* WT  = XT + szXT;                 // 768*256
    unsigned short* WoT = WT + (size_t)N3 * DD;      // 256*256
    unsigned short* AO  = WoT + (size_t)DD * DD;     // (b, 640, 256) bf16
    float* B2 = (float*)(AO + szXT);                 // (8, 640, 640) fp32, (h,i,j)

    xT_kernel     <<<dim3(10, 4, NB), 256, 0, stream>>>(x, XT);
    transpose_cast<<<dim3(12, 4, 1),  256, 0, stream>>>(w_qkv, WT, DD, N3);
    transpose_cast<<<dim3(4, 4, 1),   256, 0, stream>>>(w_out, WoT, DD, DD);
    bias2_kernel  <<<dim3(10, 10, 1), 256, 0, stream>>>(rel, table, B2);
    qkv_mfma      <<<dim3(5, 6, NB),  256, 0, stream>>>(XT, WT, Q, K, V);
    attn_kernel   <<<dim3(10, NH, NB), 256, 0, stream>>>(Q, K, V, B2, AO);
    outproj_mfma  <<<dim3(5, 2, NB),  256, 0, stream>>>(AO, WoT, out);
}